// Round 5
// baseline (444.310 us; speedup 1.0000x reference)
//
#include <hip/hip_runtime.h>

typedef _Float16 f16;
typedef f16   f16x2  __attribute__((ext_vector_type(2)));
typedef f16   f16x8  __attribute__((ext_vector_type(8)));
typedef float f32x4  __attribute__((ext_vector_type(4)));
typedef float f32x4u __attribute__((ext_vector_type(4), aligned(4)));
typedef __fp16 h16x2 __attribute__((ext_vector_type(2)));

#define T_STEPS 512
#define INPUT   12
#define HID     20
#define BATCH   16
#define LOG2E      1.4426950408889634f
#define TWO_LOG2E  2.8853900817779268f

static __device__ __forceinline__ f16x2 pk(float a, float b) {
    h16x2 r = __builtin_amdgcn_cvt_pkrtz(a, b);
    return __builtin_bit_cast(f16x2, r);
}
static __device__ __forceinline__ float sig_pre(float a) {   // a = -log2e * gate (pre-scaled)
    return __builtin_amdgcn_rcpf(1.0f + __builtin_amdgcn_exp2f(a));
}
static __device__ __forceinline__ float tanh_pre(float a) {  // a = 2*log2e * arg (pre-scaled)
    return 1.0f - 2.0f * __builtin_amdgcn_rcpf(1.0f + __builtin_amdgcn_exp2f(a));
}

// Fully wave-local LSTM: one wave owns 16 batches and ALL 80 gate rows.
// K-permutation of z=[x|h]: slot k=8q+j -> x[3q+j] (j<3), h[5q+(j-3)] (j>=3).
// W-row permutation: tile t, row 4q+r -> gate r of unit 5q+t.
// => lane (col,quad) computes h for units 5q..5q+4 of batch col, which is
//    exactly the h its own next B-fragment needs. No LDS, no barrier in loop.
__global__ __launch_bounds__(64) void lstm_kernel(
    const float* __restrict__ x,      // [8192,512,12]
    const float* __restrict__ w_ih,   // [80,12]
    const float* __restrict__ w_hh,   // [80,20]
    const float* __restrict__ b_ih,   // [80]
    const float* __restrict__ b_hh,   // [80]
    const float* __restrict__ w_out,  // [10,20]
    const float* __restrict__ b_out,  // [10]
    float* __restrict__ out)          // [8192,10]
{
    const int lane = threadIdx.x & 63;
    const int col  = lane & 15;        // batch within group / A-row
    const int quad = lane >> 4;

    // ---- A fragments: 5 tiles, lane holds W'[row=col][k=8q..8q+7] of each ----
    // gate of A-row col is g = col&3; scale folded into weights:
    // sigmoid gates (i,f,o): -log2e ; tanh gate (g): +2*log2e
    const int   g_row = col & 3;
    const float sA    = (g_row == 2) ? TWO_LOG2E : -LOG2E;

    f16x8 afragW[5];
#pragma unroll
    for (int t = 0; t < 5; ++t) {
        int u_r = 5 * (col >> 2) + t;          // unit of this A-row in tile t
        int row = g_row * HID + u_r;           // original row of [w_ih | w_hh]
        f16x8 w;
#pragma unroll
        for (int j = 0; j < 8; ++j) {
            float v = (j < 3) ? w_ih[row * INPUT + 3 * quad + j]
                              : w_hh[row * HID + 5 * quad + (j - 3)];
            w[j] = (f16)(v * sA);
        }
        afragW[t] = w;
    }

    // ---- biases as MFMA C operand (same folded scales, per gate r) ----
    f32x4 cbias[5];
#pragma unroll
    for (int t = 0; t < 5; ++t) {
        int u_b = 5 * quad + t;                // unit owned by this lane, tile t
#pragma unroll
        for (int r = 0; r < 4; ++r) {
            float s = (r == 2) ? TWO_LOG2E : -LOG2E;
            cbias[t][r] = (b_ih[r * HID + u_b] + b_hh[r * HID + u_b]) * s;
        }
    }

    // ---- x access: one (possibly 4B-aligned) dwordx4 per step covers the
    //      3 floats x[3q..3q+2]; select by quad parity ----
    const int al_words = (quad == 0) ? 0 : (quad == 1) ? 2 : (quad == 2) ? 6 : 8;
    const int sel      = quad & 1;
    const float* xp = x + (size_t)(blockIdx.x * BATCH + col) * (T_STEPS * INPUT) + al_words;

    auto loadx = [&](int t) -> f32x4 {
        return *(const f32x4u*)(xp + (size_t)t * INPUT);
    };

    // ---- B fragment (z = [x|h]) built in registers ----
    union BF { f16x8 v; f16x2 h2[4]; } bf;
    {
        f32x4 xv = loadx(0);
        float x0 = sel ? xv[1] : xv[0];
        float x1 = sel ? xv[2] : xv[1];
        float x2 = sel ? xv[3] : xv[2];
        bf.h2[0] = pk(x0, x1);
        bf.h2[1] = pk(x2, 0.f);     // h = 0 at t = -1
        bf.h2[2] = pk(0.f, 0.f);
        bf.h2[3] = pk(0.f, 0.f);
    }

    float cst[5] = {0.f, 0.f, 0.f, 0.f, 0.f};

    // 2-deep x prefetch queue (distance 2 steps ~ >1000 cy)
    f32x4 qA = loadx(1);
    f32x4 qB = loadx(2);

    auto step = [&](f32x4& q, int tl) {
        // 5 MFMAs: all gates of 16 batches; reg r of tile t = gate r, unit 5q+t
        f32x4 acc[5];
#pragma unroll
        for (int t = 0; t < 5; ++t)
            acc[t] = __builtin_amdgcn_mfma_f32_16x16x32_f16(afragW[t], bf.v, cbias[t], 0, 0, 0);

        float h[5];
#pragma unroll
        for (int t = 0; t < 5; ++t) {
            float ig = sig_pre(acc[t][0]);
            float fg = sig_pre(acc[t][1]);
            float gg = tanh_pre(acc[t][2]);
            float og = sig_pre(acc[t][3]);
            float c2 = fg * cst[t] + ig * gg;
            cst[t] = c2;
            h[t] = og * tanh_pre(TWO_LOG2E * c2);
        }

        // next x from queue; reload queue slot
        float x0 = sel ? q[1] : q[0];
        float x1 = sel ? q[2] : q[1];
        float x2 = sel ? q[3] : q[2];
        q = loadx(tl);

        // next B fragment, all in registers
        bf.h2[0] = pk(x0, x1);
        bf.h2[1] = pk(x2, h[0]);
        bf.h2[2] = pk(h[1], h[2]);
        bf.h2[3] = pk(h[3], h[4]);
    };

#pragma unroll 1
    for (int t = 0; t < T_STEPS; t += 2) {
        int l1 = t + 3; if (l1 > T_STEPS - 1) l1 = T_STEPS - 1;  // dead-but-safe clamp
        int l2 = t + 4; if (l2 > T_STEPS - 1) l2 = T_STEPS - 1;
        step(qA, l1);   // step t   : builds bf(t+1)
        step(qB, l2);   // step t+1 : builds bf(t+2)
    }
    // Final body built bf(512): slots 3..7 hold h(511) for units 5q..5q+4.

    // ---- epilogue: transpose h through tiny LDS, project to out ----
    __shared__ f16 htmp[BATCH][HID];
    htmp[col][5 * quad + 0] = bf.h2[1][1];
    htmp[col][5 * quad + 1] = bf.h2[2][0];
    htmp[col][5 * quad + 2] = bf.h2[2][1];
    htmp[col][5 * quad + 3] = bf.h2[3][0];
    htmp[col][5 * quad + 4] = bf.h2[3][1];
    __syncthreads();

#pragma unroll
    for (int base = 0; base < BATCH * 10; base += 64) {
        int idx = base + lane;
        if (idx < BATCH * 10) {
            int b = idx / 10, o = idx % 10;
            float s = b_out[o];
#pragma unroll
            for (int u = 0; u < HID; ++u)
                s += (float)htmp[b][u] * w_out[o * HID + u];
            out[(size_t)(blockIdx.x * BATCH + b) * 10 + o] = s;
        }
    }
}

extern "C" void kernel_launch(void* const* d_in, const int* in_sizes, int n_in,
                              void* d_out, int out_size, void* d_ws, size_t ws_size,
                              hipStream_t stream) {
    const float* x     = (const float*)d_in[0];
    const float* w_ih  = (const float*)d_in[1];
    const float* w_hh  = (const float*)d_in[2];
    const float* b_ih  = (const float*)d_in[3];
    const float* b_hh  = (const float*)d_in[4];
    const float* w_out = (const float*)d_in[5];
    const float* b_out = (const float*)d_in[6];
    float* out = (float*)d_out;

    const int blocks = 8192 / BATCH;   // 512 single-wave blocks -> 2 waves/CU
    hipLaunchKernelGGL(lstm_kernel, dim3(blocks), dim3(64), 0, stream,
                       x, w_ih, w_hh, b_ih, b_hh, w_out, b_out, out);
}